// Round 2
// baseline (9365.184 us; speedup 1.0000x reference)
//
#include <hip/hip_runtime.h>

// Fused persistent-weight LSTM, fp32 I/O, split-bf16 MFMA. MI355X (gfx950).
//
// Grid = 256 blocks (1/CU). blockIdx -> (mg = blk&7: row-group of 16 batch
// rows, nb = blk>>3: 16 hidden cols = 64 gate cols). 8 independent 32-block
// chains (row-groups never exchange data), each with its own monotonic
// arrival counter in d_ws. Each wave holds its K-quarter of the block's
// weight slice as bf16 hi+lo fragments in 256 VGPRs (loaded/split once,
// reused 512 steps) -> __launch_bounds__(256,1) for the 512-VGPR budget.
//
// Numerics: A (x|h) and W split as v = hi + lo (bf16 each); acc +=
// ah*wh + al*wh + ah*wl in fp32 MFMA accumulators -> ~2^-18 relative vs the
// fp32 reference (threshold 1.66e-2). h carried step-to-step as pre-split
// (hi,lo) bf16 planes in d_ws; out gets exact fp32 h and c.

typedef unsigned short u16;
typedef unsigned int   u32;
typedef short bf16x8 __attribute__((ext_vector_type(8)));
typedef float f32x4  __attribute__((ext_vector_type(4)));

#define TT 512
#define BB 128
#define DD 512
#define HH 512
#define ASTRIDE 1032   // 1024 + 8 pad bf16 (row = 2064 B: 16B-aligned, breaks pow-2 stride)

__device__ __forceinline__ float bf2f(u16 u) { return __uint_as_float(((u32)u) << 16); }
__device__ __forceinline__ u16 f2bf(float f) {
    u32 u = __float_as_uint(f);
    return (u16)((u + 0x7FFFu + ((u >> 16) & 1u)) >> 16);   // RNE
}
__device__ __forceinline__ u32 pack2(u16 a, u16 b) { return (u32)a | ((u32)b << 16); }
__device__ __forceinline__ float sigm(float x)  { return 1.0f / (1.0f + __expf(-x)); }
__device__ __forceinline__ float tanh_(float x) { return 1.0f - 2.0f / (1.0f + __expf(2.0f * x)); }

__launch_bounds__(256, 1)
__global__ void lstm_fused(const float* __restrict__ x,
                           const float* __restrict__ Wf, const float* __restrict__ bfv,
                           const float* __restrict__ Wi, const float* __restrict__ biv,
                           const float* __restrict__ Wg, const float* __restrict__ bgv,
                           const float* __restrict__ Wo, const float* __restrict__ bov,
                           float* __restrict__ out, u32* __restrict__ cnt,
                           u16* __restrict__ hbuf)
{
    __shared__ __align__(16) u16   aHi[16 * ASTRIDE];       // [16 rows][512 x | 512 h] bf16 hi
    __shared__ __align__(16) u16   aLo[16 * ASTRIDE];       // bf16 lo plane
    __shared__ __align__(16) float xchg[4 * 4 * 16 * 20];   // [wave][gate][col][row16 + 4 pad]

    const int tid  = threadIdx.x;
    const int lane = tid & 63;
    const int wv   = tid >> 6;        // wave 0..3 : K-quarter owner
    const int l16  = lane & 15;
    const int quad = lane >> 4;
    const int blk  = blockIdx.x;
    const int mg   = blk & 7;         // row-group / chain id (XCD-affine heuristic)
    const int nb   = blk >> 3;        // hidden-col slice 0..31
    const int rowbase = mg * 16;
    const int kwb  = wv * 256;

    // ---- one-time: persistent split-bf16 B fragments ----
    // frag elem j of (gate q, kstep s): W[k = kwb + s*32 + quad*8 + j][nb*16 + l16]
    const float* Wq[4] = { Wf, Wi, Wg, Wo };
    bf16x8 whi[4][8], wlo[4][8];
#pragma unroll
    for (int q = 0; q < 4; ++q) {
        const float* Wp = Wq[q] + (size_t)(kwb + quad * 8) * HH + nb * 16 + l16;
#pragma unroll
        for (int s = 0; s < 8; ++s)
#pragma unroll
            for (int j = 0; j < 8; ++j) {
                float wval = Wp[(size_t)(s * 32 + j) * HH];
                u16 h = f2bf(wval);
                whi[q][s][j] = (short)h;
                wlo[q][s][j] = (short)f2bf(wval - bf2f(h));
            }
    }

    // ---- elementwise mapping: (row er, col ec) of this block's 16x16 h-tile ----
    const int ec = tid & 15, er = tid >> 4;
    const int hcol = nb * 16 + ec;
    const float bias[4] = { bfv[hcol], biv[hcol], bgv[hcol], bov[hcol] };
    float cst = 0.0f;                 // c-state lives in a register all 512 steps

    u32* myCnt = cnt + mg * 32;       // 128 B-spaced per-chain counter
    const int frow = tid >> 4;        // LDS-fill row 0..15
    const int fch  = tid & 15;        // 32-elem chunk within row half
    const u16* aHiB = aHi + l16 * ASTRIDE + kwb + quad * 8;
    const u16* aLoB = aLo + l16 * ASTRIDE + kwb + quad * 8;

    for (int t = 0; t < TT; ++t) {
        // ---- stage A = [x_t | h_{t-1}] (split hi/lo) for our 16 rows ----
        {
            u16* rowHi = aHi + frow * ASTRIDE;
            u16* rowLo = aLo + frow * ASTRIDE;
            const float4* xs = (const float4*)(x + ((size_t)t * BB + rowbase + frow) * DD + fch * 32);
#pragma unroll
            for (int g = 0; g < 4; ++g) {
                float4 a = xs[2 * g], b = xs[2 * g + 1];
                u16 h0 = f2bf(a.x), h1 = f2bf(a.y), h2 = f2bf(a.z), h3 = f2bf(a.w);
                u16 h4 = f2bf(b.x), h5 = f2bf(b.y), h6 = f2bf(b.z), h7 = f2bf(b.w);
                uint4 H = { pack2(h0, h1), pack2(h2, h3), pack2(h4, h5), pack2(h6, h7) };
                uint4 L = { pack2(f2bf(a.x - bf2f(h0)), f2bf(a.y - bf2f(h1))),
                            pack2(f2bf(a.z - bf2f(h2)), f2bf(a.w - bf2f(h3))),
                            pack2(f2bf(b.x - bf2f(h4)), f2bf(b.y - bf2f(h5))),
                            pack2(f2bf(b.z - bf2f(h6)), f2bf(b.w - bf2f(h7))) };
                ((uint4*)(rowHi + fch * 32))[g] = H;
                ((uint4*)(rowLo + fch * 32))[g] = L;
            }
            uint4* dH = (uint4*)(rowHi + 512 + fch * 32);
            uint4* dL = (uint4*)(rowLo + 512 + fch * 32);
            if (t == 0) {
                uint4 z = { 0u, 0u, 0u, 0u };
#pragma unroll
                for (int i = 0; i < 4; ++i) { dH[i] = z; dL[i] = z; }
            } else {
                const u16* hb = hbuf + (size_t)((t - 1) & 1) * (2 * BB * HH);
                const uint4* sH = (const uint4*)(hb + (rowbase + frow) * HH + fch * 32);
                const uint4* sL = (const uint4*)(hb + BB * HH + (rowbase + frow) * HH + fch * 32);
#pragma unroll
                for (int i = 0; i < 4; ++i) { dH[i] = sH[i]; dL[i] = sL[i]; }
            }
        }
        __syncthreads();

        // ---- MFMA: this wave's K-quarter, 3 split terms x 4 gates x 8 ksteps ----
        f32x4 acc[4];
#pragma unroll
        for (int q = 0; q < 4; ++q) acc[q] = (f32x4){0.f, 0.f, 0.f, 0.f};
#pragma unroll
        for (int s = 0; s < 8; ++s) {
            bf16x8 ah = *(const bf16x8*)(aHiB + s * 32);    // ds_read_b128
            bf16x8 al = *(const bf16x8*)(aLoB + s * 32);
#pragma unroll
            for (int q = 0; q < 4; ++q) {
                acc[q] = __builtin_amdgcn_mfma_f32_16x16x32_bf16(ah, whi[q][s], acc[q], 0, 0, 0);
                acc[q] = __builtin_amdgcn_mfma_f32_16x16x32_bf16(al, whi[q][s], acc[q], 0, 0, 0);
                acc[q] = __builtin_amdgcn_mfma_f32_16x16x32_bf16(ah, wlo[q][s], acc[q], 0, 0, 0);
            }
        }
        // C/D layout: col = lane&15, row = quad*4 + reg -> xchg[wave][gate][col][row]
#pragma unroll
        for (int q = 0; q < 4; ++q)
            *(f32x4*)&xchg[((wv * 4 + q) * 16 + l16) * 20 + quad * 4] = acc[q];
        __syncthreads();

        // ---- gates (one (er,ec) element per thread), fp32 ----
        float pre[4];
#pragma unroll
        for (int q = 0; q < 4; ++q) {
            float p = bias[q];
#pragma unroll
            for (int ww = 0; ww < 4; ++ww) p += xchg[((ww * 4 + q) * 16 + ec) * 20 + er];
            pre[q] = p;
        }
        float fg = sigm(pre[0]);
        float ig = sigm(pre[1]);
        float gg = tanh_(pre[2]);
        float og = sigm(pre[3]);
        cst = fg * cst + ig * gg;
        float hv = og * tanh_(cst);

        const int gidx = (rowbase + er) * HH + hcol;
        out[(size_t)t * (BB * HH) + gidx] = hv;             // outputs[t], exact fp32
        u16 hh = f2bf(hv);
        u16 hl = f2bf(hv - bf2f(hh));
        u16* hb = hbuf + (size_t)(t & 1) * (2 * BB * HH);   // ping-pong, pre-split planes
        hb[gidx] = hh;
        hb[BB * HH + gidx] = hl;
        if (t == TT - 1) {
            out[(size_t)TT * (BB * HH) + gidx] = hv;                  // hx
            out[(size_t)TT * (BB * HH) + BB * HH + gidx] = cst;       // cx
        }
        __syncthreads();   // drains vmcnt per wave before barrier

        // ---- chain barrier: 32 blocks of this row-group, monotonic counter ----
        if (tid == 0) {
            __builtin_amdgcn_fence(__ATOMIC_RELEASE, "agent");
            __hip_atomic_fetch_add(myCnt, 1u, __ATOMIC_RELAXED, __HIP_MEMORY_SCOPE_AGENT);
        }
        if (wv == 0) {
            const u32 tgt = 32u * (u32)(t + 1);
            while (__hip_atomic_load(myCnt, __ATOMIC_RELAXED, __HIP_MEMORY_SCOPE_AGENT) < tgt)
                __builtin_amdgcn_s_sleep(1);
        }
        __syncthreads();
        __builtin_amdgcn_fence(__ATOMIC_ACQUIRE, "agent"); // invalidate stale h lines
    }
}

extern "C" void kernel_launch(void* const* d_in, const int* in_sizes, int n_in,
                              void* d_out, int out_size, void* d_ws, size_t ws_size,
                              hipStream_t stream) {
    (void)in_sizes; (void)n_in; (void)out_size; (void)ws_size;
    const float* x   = (const float*)d_in[0];
    const float* Wf  = (const float*)d_in[1];
    const float* bfv = (const float*)d_in[2];
    const float* Wi  = (const float*)d_in[3];
    const float* biv = (const float*)d_in[4];
    const float* Wg  = (const float*)d_in[5];
    const float* bgv = (const float*)d_in[6];
    const float* Wo  = (const float*)d_in[7];
    const float* bov = (const float*)d_in[8];

    u32* cnt  = (u32*)d_ws;                    // 8 chain counters, 128 B apart
    u16* hbuf = (u16*)((char*)d_ws + 1024);    // 2 x (hi,lo) planes of [128][512] bf16

    hipMemsetAsync(d_ws, 0, 1024, stream);     // zero counters (ws re-poisoned 0xAA)
    lstm_fused<<<dim3(256), dim3(256), 0, stream>>>(x, Wf, bfv, Wi, biv, Wg, bgv, Wo, bov,
                                                    (float*)d_out, cnt, hbuf);
}

// Round 3
// 4729.842 us; speedup vs baseline: 1.9800x; 1.9800x over previous
//
#include <hip/hip_runtime.h>

// Fused persistent-weight LSTM, fp32 I/O, split-bf16 MFMA. MI355X (gfx950).
//
// Grid = 256 blocks (1/CU). blockIdx -> (mg = blk&7: row-group of 16 batch
// rows, nb = blk>>3: 16 hidden cols = 64 gate cols). 8 independent 32-block
// chains, each with its own monotonic arrival counter in d_ws. Each wave
// holds its K-quarter of the block's weight slice as bf16 hi+lo fragments in
// 256 VGPRs (loaded once, reused 512 steps).
//
// R3 change: NO agent fences (R2's buffer_wbl2/buffer_inv per block-step was
// ~17 us/step). h-exchange is per-instruction coherent instead: h stored as
// relaxed AGENT-scope atomic u32 (hi|lo packed, global_store sc0 sc1 ->
// write-through), read via relaxed AGENT-scope b64 atomic loads (bypass
// stale L1/L2). __syncthreads drains vmcnt before the relaxed counter-add,
// so stores are at the coherence point before the arrive is visible.
//
// Numerics: v = hi + lo (bf16 each); acc += ah*wh + al*wh + ah*wl in fp32
// MFMA accumulators (verified absmax 2e-3 vs threshold 1.66e-2).

typedef unsigned short u16;
typedef unsigned int   u32;
typedef unsigned long long u64;
typedef short bf16x8 __attribute__((ext_vector_type(8)));
typedef float f32x4  __attribute__((ext_vector_type(4)));

#define TT 512
#define BB 128
#define DD 512
#define HH 512
#define ASTRIDE 1032   // 1024 + 8 pad bf16 (row = 2064 B: 16B-aligned, breaks pow-2 stride)

__device__ __forceinline__ float bf2f(u16 u) { return __uint_as_float(((u32)u) << 16); }
__device__ __forceinline__ u16 f2bf(float f) {
    u32 u = __float_as_uint(f);
    return (u16)((u + 0x7FFFu + ((u >> 16) & 1u)) >> 16);   // RNE
}
__device__ __forceinline__ u32 pack2(u16 a, u16 b) { return (u32)a | ((u32)b << 16); }
__device__ __forceinline__ float sigm(float x)  { return 1.0f / (1.0f + __expf(-x)); }
__device__ __forceinline__ float tanh_(float x) { return 1.0f - 2.0f / (1.0f + __expf(2.0f * x)); }

__launch_bounds__(256, 1)
__global__ void lstm_fused(const float* __restrict__ x,
                           const float* __restrict__ Wf, const float* __restrict__ bfv,
                           const float* __restrict__ Wi, const float* __restrict__ biv,
                           const float* __restrict__ Wg, const float* __restrict__ bgv,
                           const float* __restrict__ Wo, const float* __restrict__ bov,
                           float* __restrict__ out, u32* __restrict__ cnt,
                           u32* __restrict__ hbuf)
{
    __shared__ __align__(16) u16   aHi[16 * ASTRIDE];       // [16 rows][512 x | 512 h] bf16 hi
    __shared__ __align__(16) u16   aLo[16 * ASTRIDE];       // bf16 lo plane
    __shared__ __align__(16) float xchg[4 * 4 * 16 * 20];   // [wave][gate][col][row16 + 4 pad]

    const int tid  = threadIdx.x;
    const int lane = tid & 63;
    const int wv   = tid >> 6;        // wave 0..3 : K-quarter owner
    const int l16  = lane & 15;
    const int quad = lane >> 4;
    const int blk  = blockIdx.x;
    const int mg   = blk & 7;         // row-group / chain id (XCD-affine heuristic)
    const int nb   = blk >> 3;        // hidden-col slice 0..31
    const int rowbase = mg * 16;
    const int kwb  = wv * 256;

    // ---- one-time: persistent split-bf16 B fragments ----
    // frag elem j of (gate q, kstep s): W[k = kwb + s*32 + quad*8 + j][nb*16 + l16]
    const float* Wq[4] = { Wf, Wi, Wg, Wo };
    bf16x8 whi[4][8], wlo[4][8];
#pragma unroll
    for (int q = 0; q < 4; ++q) {
        const float* Wp = Wq[q] + (size_t)(kwb + quad * 8) * HH + nb * 16 + l16;
#pragma unroll
        for (int s = 0; s < 8; ++s)
#pragma unroll
            for (int j = 0; j < 8; ++j) {
                float wval = Wp[(size_t)(s * 32 + j) * HH];
                u16 h = f2bf(wval);
                whi[q][s][j] = (short)h;
                wlo[q][s][j] = (short)f2bf(wval - bf2f(h));
            }
    }

    // ---- elementwise mapping: (row er, col ec) of this block's 16x16 h-tile ----
    const int ec = tid & 15, er = tid >> 4;
    const int hcol = nb * 16 + ec;
    const float bias[4] = { bfv[hcol], biv[hcol], bgv[hcol], bov[hcol] };
    float cst = 0.0f;                 // c-state lives in a register all 512 steps

    u32* myCnt = cnt + mg * 32;       // 128 B-spaced per-chain counter
    const int frow = tid >> 4;        // LDS-fill row 0..15
    const int fch  = tid & 15;        // 32-elem chunk within row half
    const u16* aHiB = aHi + l16 * ASTRIDE + kwb + quad * 8;
    const u16* aLoB = aLo + l16 * ASTRIDE + kwb + quad * 8;

    for (int t = 0; t < TT; ++t) {
        // ---- stage A = [x_t | h_{t-1}] (split hi/lo) for our 16 rows ----
        {
            u16* rowHi = aHi + frow * ASTRIDE;
            u16* rowLo = aLo + frow * ASTRIDE;
            const float4* xs = (const float4*)(x + ((size_t)t * BB + rowbase + frow) * DD + fch * 32);
#pragma unroll
            for (int g = 0; g < 4; ++g) {
                float4 a = xs[2 * g], b = xs[2 * g + 1];
                u16 h0 = f2bf(a.x), h1 = f2bf(a.y), h2 = f2bf(a.z), h3 = f2bf(a.w);
                u16 h4 = f2bf(b.x), h5 = f2bf(b.y), h6 = f2bf(b.z), h7 = f2bf(b.w);
                uint4 H = { pack2(h0, h1), pack2(h2, h3), pack2(h4, h5), pack2(h6, h7) };
                uint4 L = { pack2(f2bf(a.x - bf2f(h0)), f2bf(a.y - bf2f(h1))),
                            pack2(f2bf(a.z - bf2f(h2)), f2bf(a.w - bf2f(h3))),
                            pack2(f2bf(b.x - bf2f(h4)), f2bf(b.y - bf2f(h5))),
                            pack2(f2bf(b.z - bf2f(h6)), f2bf(b.w - bf2f(h7))) };
                ((uint4*)(rowHi + fch * 32))[g] = H;
                ((uint4*)(rowLo + fch * 32))[g] = L;
            }
            uint4* dH = (uint4*)(rowHi + 512 + fch * 32);
            uint4* dL = (uint4*)(rowLo + 512 + fch * 32);
            if (t == 0) {
                uint4 z = { 0u, 0u, 0u, 0u };
#pragma unroll
                for (int i = 0; i < 4; ++i) { dH[i] = z; dL[i] = z; }
            } else {
                // coherent read of packed h (hi|lo u32), b64 atomic loads bypass L1/L2
                const u64* hs = (const u64*)(hbuf + (size_t)((t - 1) & 1) * (BB * HH)
                                             + (size_t)(rowbase + frow) * HH + fch * 32);
                u32 hhp[16], hlp[16];
#pragma unroll
                for (int i = 0; i < 16; ++i) {
                    u64 v = __hip_atomic_load(hs + i, __ATOMIC_RELAXED, __HIP_MEMORY_SCOPE_AGENT);
                    u32 c0 = (u32)v, c1 = (u32)(v >> 32);
                    hhp[i] = (c0 & 0xFFFFu) | (c1 << 16);
                    hlp[i] = (c0 >> 16) | (c1 & 0xFFFF0000u);
                }
#pragma unroll
                for (int i = 0; i < 4; ++i) {
                    dH[i] = (uint4){ hhp[4*i], hhp[4*i+1], hhp[4*i+2], hhp[4*i+3] };
                    dL[i] = (uint4){ hlp[4*i], hlp[4*i+1], hlp[4*i+2], hlp[4*i+3] };
                }
            }
        }
        __syncthreads();

        // ---- MFMA: this wave's K-quarter, 3 split terms x 4 gates x 8 ksteps ----
        f32x4 acc[4];
#pragma unroll
        for (int q = 0; q < 4; ++q) acc[q] = (f32x4){0.f, 0.f, 0.f, 0.f};
#pragma unroll
        for (int s = 0; s < 8; ++s) {
            bf16x8 ah = *(const bf16x8*)(aHiB + s * 32);    // ds_read_b128
            bf16x8 al = *(const bf16x8*)(aLoB + s * 32);
#pragma unroll
            for (int q = 0; q < 4; ++q) {
                acc[q] = __builtin_amdgcn_mfma_f32_16x16x32_bf16(ah, whi[q][s], acc[q], 0, 0, 0);
                acc[q] = __builtin_amdgcn_mfma_f32_16x16x32_bf16(al, whi[q][s], acc[q], 0, 0, 0);
                acc[q] = __builtin_amdgcn_mfma_f32_16x16x32_bf16(ah, wlo[q][s], acc[q], 0, 0, 0);
            }
        }
        // C/D layout: col = lane&15, row = quad*4 + reg -> xchg[wave][gate][col][row]
#pragma unroll
        for (int q = 0; q < 4; ++q)
            *(f32x4*)&xchg[((wv * 4 + q) * 16 + l16) * 20 + quad * 4] = acc[q];
        __syncthreads();

        // ---- gates (one (er,ec) element per thread), fp32 ----
        float pre[4];
#pragma unroll
        for (int q = 0; q < 4; ++q) {
            float p = bias[q];
#pragma unroll
            for (int ww = 0; ww < 4; ++ww) p += xchg[((ww * 4 + q) * 16 + ec) * 20 + er];
            pre[q] = p;
        }
        float fg = sigm(pre[0]);
        float ig = sigm(pre[1]);
        float gg = tanh_(pre[2]);
        float og = sigm(pre[3]);
        cst = fg * cst + ig * gg;
        float hv = og * tanh_(cst);

        const int gidx = (rowbase + er) * HH + hcol;
        out[(size_t)t * (BB * HH) + gidx] = hv;             // outputs[t], exact fp32 (plain store)
        u16 hh = f2bf(hv);
        u16 hl = f2bf(hv - bf2f(hh));
        // coherent write-through of packed h (no fence needed later)
        __hip_atomic_store(hbuf + (size_t)(t & 1) * (BB * HH) + gidx, pack2(hh, hl),
                           __ATOMIC_RELAXED, __HIP_MEMORY_SCOPE_AGENT);
        if (t == TT - 1) {
            out[(size_t)TT * (BB * HH) + gidx] = hv;                  // hx
            out[(size_t)TT * (BB * HH) + BB * HH + gidx] = cst;       // cx
        }
        __syncthreads();   // drains vmcnt(0) per wave: h stores acked at coherence point

        // ---- chain barrier: 32 blocks of this row-group, monotonic counter ----
        if (tid == 0)
            __hip_atomic_fetch_add(myCnt, 1u, __ATOMIC_RELAXED, __HIP_MEMORY_SCOPE_AGENT);
        if (wv == 0) {
            const u32 tgt = 32u * (u32)(t + 1);
            while (__hip_atomic_load(myCnt, __ATOMIC_RELAXED, __HIP_MEMORY_SCOPE_AGENT) < tgt)
                __builtin_amdgcn_s_sleep(1);
        }
        __syncthreads();
    }
}

extern "C" void kernel_launch(void* const* d_in, const int* in_sizes, int n_in,
                              void* d_out, int out_size, void* d_ws, size_t ws_size,
                              hipStream_t stream) {
    (void)in_sizes; (void)n_in; (void)out_size; (void)ws_size;
    const float* x   = (const float*)d_in[0];
    const float* Wf  = (const float*)d_in[1];
    const float* bfv = (const float*)d_in[2];
    const float* Wi  = (const float*)d_in[3];
    const float* biv = (const float*)d_in[4];
    const float* Wg  = (const float*)d_in[5];
    const float* bgv = (const float*)d_in[6];
    const float* Wo  = (const float*)d_in[7];
    const float* bov = (const float*)d_in[8];

    u32* cnt  = (u32*)d_ws;                    // 8 chain counters, 128 B apart
    u32* hbuf = (u32*)((char*)d_ws + 1024);    // 2 x [128][512] packed (hi|lo) u32

    hipMemsetAsync(d_ws, 0, 1024, stream);     // zero counters (ws re-poisoned 0xAA)
    lstm_fused<<<dim3(256), dim3(256), 0, stream>>>(x, Wf, bfv, Wi, biv, Wg, bgv, Wo, bov,
                                                    (float*)d_out, cnt, hbuf);
}